// Round 7
// baseline (1126.022 us; speedup 1.0000x reference)
//
#include <hip/hip_runtime.h>

// Qwen3.5 GatedDeltaNet fwd on gfx950 — chunked delta-rule + tiled MFMA GEMMs.
// B=2 T=2048 HID=2048 HK=16 HV=32 DK=DV=128 KW=4, chunk C=64 (32 chunks).
// R6: gemm512 (512x256, BK=32, K-major chunk LDS, 16 waves) for GEMM1.

#define T_LEN 2048
#define MROWS 4096

typedef __bf16 bf16x8 __attribute__((ext_vector_type(8)));
typedef float f32x4 __attribute__((ext_vector_type(4)));

#define MFMA(a, b, c) __builtin_amdgcn_mfma_f32_16x16x32_bf16((a), (b), (c), 0, 0, 0)

__device__ __forceinline__ unsigned short f2bf(float f) {
  unsigned int u = __float_as_uint(f);
  unsigned int r = (u + 0x7fffu + ((u >> 16) & 1u)) >> 16;
  return (unsigned short)r;
}
__device__ __forceinline__ float bf2f(unsigned short u) {
  return __uint_as_float(((unsigned int)u) << 16);
}
__device__ __forceinline__ void gload_lds16(const void* g, void* l) {
  __builtin_amdgcn_global_load_lds(
      (const __attribute__((address_space(1))) unsigned int*)g,
      (__attribute__((address_space(3))) unsigned int*)l, 16, 0, 0);
}

// ---------------- elementwise f32 -> bf16 ----------------
__global__ __launch_bounds__(256) void f32_to_bf16_vec(const float* __restrict__ src,
                                                       unsigned short* __restrict__ dst,
                                                       int n4) {
  int i = blockIdx.x * 256 + threadIdx.x;
  if (i >= n4) return;
  float4 v = ((const float4*)src)[i];
  ushort4 o;
  o.x = f2bf(v.x); o.y = f2bf(v.y); o.z = f2bf(v.z); o.w = f2bf(v.w);
  ((ushort4*)dst)[i] = o;
}

// ---------------- transpose f32 [R,C] -> bf16 [C,R] ----------------
__global__ __launch_bounds__(256) void transpose_f2b(const float* __restrict__ src,
                                                     unsigned short* __restrict__ dst,
                                                     int R, int C) {
  __shared__ float tile[32][33];
  int tx = threadIdx.x & 31, ty = threadIdx.x >> 5;
  int c0 = blockIdx.x * 32, r0 = blockIdx.y * 32;
  #pragma unroll
  for (int i = ty; i < 32; i += 8)
    tile[i][tx] = src[(size_t)(r0 + i) * C + c0 + tx];
  __syncthreads();
  #pragma unroll
  for (int i = ty; i < 32; i += 8)
    dst[(size_t)(c0 + i) * R + r0 + tx] = f2bf(tile[tx][i]);
}

// ===================== 512x256 GEMM, BK=32, K-major chunk LDS =====================
// C[M,N] = A[M,K](lda) @ Bt[N,K](ldb)^T.  1024 thr = 16 waves (4m x 4n), per-wave 128x64.
// LDS buffer (48KB): A chunks [kc0..3][row0..511] 16B each; B at +32KB [kc][col].
// Conflict-free frag reads (16 consecutive chunks per 16-lane group).
template <int OUTBF>
__global__ __launch_bounds__(1024, 1) void gemm512(const unsigned short* __restrict__ A, int lda,
                                                   const unsigned short* __restrict__ Bt, int ldb,
                                                   void* __restrict__ Cv, int ldc,
                                                   int M, int N, int K) {
  constexpr int BUFSH = 24576;   // ushorts per buffer (48 KB)
  __shared__ unsigned short lds[2 * BUFSH];

  const int mtiles = M >> 9;
  const int nwg = gridDim.x;
  const int orig = blockIdx.x;
  const int q = nwg >> 3, r = nwg & 7;
  const int xcd = orig & 7, idx = orig >> 3;
  const int swz = (xcd < r ? xcd * (q + 1) : r * (q + 1) + (xcd - r) * q) + idx;
  const int m0 = (swz % mtiles) * 512;
  const int n0 = (swz / mtiles) * 256;

  const int tid = threadIdx.x, lane = tid & 63, wv = tid >> 6;   // 16 waves
  const int wm = wv >> 2, wn = wv & 3;
  const int l15 = lane & 15, l4 = lane >> 4;

  f32x4 acc[8][4];
  #pragma unroll
  for (int i = 0; i < 8; i++)
    #pragma unroll
    for (int j = 0; j < 4; j++) acc[i][j] = f32x4{0.f, 0.f, 0.f, 0.f};

  const int NT = K >> 5;

  auto STAGE = [&](int kt) {
    unsigned short* base = lds + (kt & 1) * BUFSH;
    const int k0 = kt << 5;
    // A: 2048 chunks (kc=c>>9, row=c&511), 2 issues
    #pragma unroll
    for (int is = 0; is < 2; is++) {
      int c = is * 1024 + tid;
      int kc = c >> 9, row = c & 511;
      gload_lds16(A + (size_t)(m0 + row) * lda + k0 + kc * 8,
                  base + is * 8192 + wv * 512);
    }
    // B: 1024 chunks (kc=c>>8, col=c&255), 1 issue
    {
      int kc = tid >> 8, col = tid & 255;
      gload_lds16(Bt + (size_t)(n0 + col) * ldb + k0 + kc * 8,
                  base + 16384 + wv * 512);
    }
  };

  STAGE(0);
  if (NT > 1) STAGE(1);
  asm volatile("s_waitcnt vmcnt(3)" ::: "memory");
  __builtin_amdgcn_sched_barrier(0);
  __builtin_amdgcn_s_barrier();
  __builtin_amdgcn_sched_barrier(0);

  for (int t = 0; t < NT; t++) {
    const unsigned short* buf = lds + (t & 1) * BUFSH;
    // B frags: chunk (kc=l4, col=wn*64+n*16+l15)
    bf16x8 bF[4];
    #pragma unroll
    for (int n = 0; n < 4; n++)
      bF[n] = *(const bf16x8*)(buf + 16384 + (size_t)(l4 * 256 + wn * 64 + n * 16 + l15) * 8);
    __builtin_amdgcn_s_setprio(1);
    #pragma unroll
    for (int m = 0; m < 8; m++) {
      bf16x8 aF = *(const bf16x8*)(buf + (size_t)(l4 * 512 + wm * 128 + m * 16 + l15) * 8);
      #pragma unroll
      for (int n = 0; n < 4; n++) acc[m][n] = MFMA(aF, bF[n], acc[m][n]);
    }
    __builtin_amdgcn_s_setprio(0);
    __builtin_amdgcn_sched_barrier(0);
    __builtin_amdgcn_s_barrier();          // all reads of buf[t&1] done
    __builtin_amdgcn_sched_barrier(0);
    if (t + 2 < NT) STAGE(t + 2);
    if (t + 1 < NT) {
      if (t + 2 < NT) asm volatile("s_waitcnt vmcnt(3)" ::: "memory");
      else            asm volatile("s_waitcnt vmcnt(0)" ::: "memory");
      __builtin_amdgcn_sched_barrier(0);
      __builtin_amdgcn_s_barrier();        // buf[(t+1)&1] fully staged
      __builtin_amdgcn_sched_barrier(0);
    }
  }

  #pragma unroll
  for (int m = 0; m < 8; m++) {
    int grow = m0 + wm * 128 + m * 16 + l4 * 4;
    #pragma unroll
    for (int n = 0; n < 4; n++) {
      int gcol = n0 + wn * 64 + n * 16 + l15;
      if (OUTBF) {
        unsigned short* cp = (unsigned short*)Cv + (size_t)grow * ldc + gcol;
        #pragma unroll
        for (int rr = 0; rr < 4; rr++) cp[(size_t)rr * ldc] = f2bf(acc[m][n][rr]);
      } else {
        float* cp = (float*)Cv + (size_t)grow * ldc + gcol;
        #pragma unroll
        for (int rr = 0; rr < 4; rr++) cp[(size_t)rr * ldc] = acc[m][n][rr];
      }
    }
  }
}

// ===================== 256-wide-tile GEMM, counted-vmcnt pipeline =====================
template <int OUTBF, int BN>
__global__ __launch_bounds__(512, 2) void gemm256(const unsigned short* __restrict__ A, int lda,
                                                  const unsigned short* __restrict__ Bt, int ldb,
                                                  void* __restrict__ Cv, int ldc,
                                                  int M, int N, int K) {
  constexpr int BUFSZ = 16384 + BN * 64;
  constexpr int BISS = BN / 64;
  constexpr int IS = 4 + BISS;
  constexpr int WMv = (BN == 256) ? 2 : 4;
  constexpr int MSUB = 256 / (WMv * 16);
  constexpr int MSPAN = 256 / WMv;

  __shared__ unsigned short lds[2 * BUFSZ];

  const int mtiles = M >> 8;
  const int nwg = gridDim.x;
  const int orig = blockIdx.x;
  const int q = nwg >> 3, r = nwg & 7;
  const int xcd = orig & 7, idx = orig >> 3;
  const int swz = (xcd < r ? xcd * (q + 1) : r * (q + 1) + (xcd - r) * q) + idx;
  const int m0 = (swz % mtiles) * 256;
  const int n0 = (swz / mtiles) * BN;

  const int tid = threadIdx.x, lane = tid & 63, wv = tid >> 6;
  const int wm = (BN == 256) ? (wv >> 2) : (wv >> 1);
  const int wn = (BN == 256) ? (wv & 3) : (wv & 1);
  const int l15 = lane & 15, l4 = lane >> 4;

  f32x4 acc[MSUB][4];
  #pragma unroll
  for (int i = 0; i < MSUB; i++)
    #pragma unroll
    for (int j = 0; j < 4; j++) acc[i][j] = f32x4{0.f, 0.f, 0.f, 0.f};

  const int NT = K >> 6;

  auto STAGE = [&](int kt) {
    unsigned short* base = lds + (kt & 1) * BUFSZ;
    const int k0 = kt << 6;
    #pragma unroll
    for (int is = 0; is < 4; is++) {
      int ow = is * 8192 + wv * 1024;
      int o = ow + lane * 16;
      int row = o >> 7, colB = o & 127;
      int scol = colB ^ ((row & 7) << 4);
      gload_lds16(A + (size_t)(m0 + row) * lda + k0 + (scol >> 1), base + (ow >> 1));
    }
    #pragma unroll
    for (int is = 0; is < BISS; is++) {
      int ow = is * 8192 + wv * 1024;
      int o = ow + lane * 16;
      int row = o >> 7, colB = o & 127;
      int scol = colB ^ ((row & 7) << 4);
      gload_lds16(Bt + (size_t)(n0 + row) * ldb + k0 + (scol >> 1), base + 16384 + (ow >> 1));
    }
  };

  STAGE(0);
  if (NT > 1) STAGE(1);
  if constexpr (IS == 8) asm volatile("s_waitcnt vmcnt(8)" ::: "memory");
  else                   asm volatile("s_waitcnt vmcnt(6)" ::: "memory");
  __builtin_amdgcn_sched_barrier(0);
  __builtin_amdgcn_s_barrier();
  __builtin_amdgcn_sched_barrier(0);

  for (int t = 0; t < NT; t++) {
    const unsigned short* Abuf = lds + (t & 1) * BUFSZ;
    const unsigned short* Bbuf = Abuf + 16384;
    bf16x8 bF[4][2];
    #pragma unroll
    for (int n = 0; n < 4; n++) {
      int rb = wn * 64 + n * 16 + l15;
      int sw = (rb & 7) << 4;
      #pragma unroll
      for (int ks = 0; ks < 2; ks++) {
        int colB = (ks * 32 + l4 * 8) * 2;
        bF[n][ks] = *(const bf16x8*)(Bbuf + rb * 64 + ((colB ^ sw) >> 1));
      }
    }
    __builtin_amdgcn_s_setprio(1);
    #pragma unroll
    for (int m = 0; m < MSUB; m++) {
      int ra = wm * MSPAN + m * 16 + l15;
      int sw = (ra & 7) << 4;
      int c0b = l4 * 16;
      bf16x8 a0 = *(const bf16x8*)(Abuf + ra * 64 + ((c0b ^ sw) >> 1));
      bf16x8 a1 = *(const bf16x8*)(Abuf + ra * 64 + (((64 + c0b) ^ sw) >> 1));
      #pragma unroll
      for (int n = 0; n < 4; n++) {
        acc[m][n] = MFMA(a0, bF[n][0], acc[m][n]);
        acc[m][n] = MFMA(a1, bF[n][1], acc[m][n]);
      }
    }
    __builtin_amdgcn_s_setprio(0);
    __builtin_amdgcn_sched_barrier(0);
    __builtin_amdgcn_s_barrier();
    __builtin_amdgcn_sched_barrier(0);
    if (t + 2 < NT) STAGE(t + 2);
    if (t + 1 < NT) {
      if (t + 2 < NT) {
        if constexpr (IS == 8) asm volatile("s_waitcnt vmcnt(8)" ::: "memory");
        else                   asm volatile("s_waitcnt vmcnt(6)" ::: "memory");
      } else {
        asm volatile("s_waitcnt vmcnt(0)" ::: "memory");
      }
      __builtin_amdgcn_sched_barrier(0);
      __builtin_amdgcn_s_barrier();
      __builtin_amdgcn_sched_barrier(0);
    }
  }

  #pragma unroll
  for (int m = 0; m < MSUB; m++) {
    int grow = m0 + wm * MSPAN + m * 16 + l4 * 4;
    #pragma unroll
    for (int n = 0; n < 4; n++) {
      int gcol = n0 + wn * 64 + n * 16 + l15;
      if (OUTBF) {
        unsigned short* cp = (unsigned short*)Cv + (size_t)grow * ldc + gcol;
        #pragma unroll
        for (int rr = 0; rr < 4; rr++) cp[(size_t)rr * ldc] = f2bf(acc[m][n][rr]);
      } else {
        float* cp = (float*)Cv + (size_t)grow * ldc + gcol;
        #pragma unroll
        for (int rr = 0; rr < 4; rr++) cp[(size_t)rr * ldc] = acc[m][n][rr];
      }
    }
  }
}

// ------- bf16 MFMA GEMM (128^2, small-N fallback) -------
template <int OUTBF>
__global__ __launch_bounds__(256) void gemm_bf16(const unsigned short* __restrict__ A, int lda,
                                                 const unsigned short* __restrict__ Bt, int ldb,
                                                 void* __restrict__ Cv, int ldc,
                                                 int M, int N, int K) {
  __shared__ unsigned short As[128 * 64];
  __shared__ unsigned short Bs[128 * 64];
  const int tid = threadIdx.x, lane = tid & 63, wv = tid >> 6;
  const int wr = wv >> 1, wc = wv & 1;
  const int m0 = blockIdx.y * 128, n0 = blockIdx.x * 128;
  const int lrow8 = lane >> 3;
  const int lk8 = (lane & 7) * 8;

  f32x4 acc[4][4];
  #pragma unroll
  for (int i = 0; i < 4; i++)
    #pragma unroll
    for (int j = 0; j < 4; j++) acc[i][j] = f32x4{0.f, 0.f, 0.f, 0.f};

  for (int k0 = 0; k0 < K; k0 += 64) {
    #pragma unroll
    for (int j = 0; j < 4; ++j) {
      int chunk = j * 4 + wv;
      int r = chunk * 8 + lrow8;
      gload_lds16(A + (size_t)(m0 + r) * lda + k0 + lk8, (void*)(As + chunk * 512));
      gload_lds16(Bt + (size_t)(n0 + r) * ldb + k0 + lk8, (void*)(Bs + chunk * 512));
    }
    __syncthreads();
    #pragma unroll
    for (int half = 0; half < 2; ++half) {
      int ko = half * 32 + (lane >> 4) * 8;
      bf16x8 af[4], bfr[4];
      #pragma unroll
      for (int i = 0; i < 4; i++) {
        int ra = wr * 64 + i * 16 + (lane & 15);
        af[i] = *(const bf16x8*)(As + ra * 64 + ko);
        int rb = wc * 64 + i * 16 + (lane & 15);
        bfr[i] = *(const bf16x8*)(Bs + rb * 64 + ko);
      }
      #pragma unroll
      for (int i = 0; i < 4; i++)
        #pragma unroll
        for (int j = 0; j < 4; j++)
          acc[i][j] = MFMA(af[i], bfr[j], acc[i][j]);
    }
    __syncthreads();
  }
  int cr4 = (lane >> 4) * 4;
  int cc = lane & 15;
  #pragma unroll
  for (int i = 0; i < 4; i++) {
    int row = m0 + wr * 64 + i * 16 + cr4;
    #pragma unroll
    for (int j = 0; j < 4; j++) {
      int col = n0 + wc * 64 + j * 16 + cc;
      if (OUTBF) {
        unsigned short* cp = (unsigned short*)Cv + (size_t)row * ldc + col;
        #pragma unroll
        for (int r = 0; r < 4; r++) cp[(size_t)r * ldc] = f2bf(acc[i][j][r]);
      } else {
        float* cp = (float*)Cv + (size_t)row * ldc + col;
        #pragma unroll
        for (int r = 0; r < 4; r++) cp[(size_t)r * ldc] = acc[i][j][r];
      }
    }
  }
}

// ---------------- beta / g from ba ----------------
__global__ __launch_bounds__(256) void beta_g_kernel(const unsigned short* __restrict__ ba,
                                                     const float* __restrict__ A_log,
                                                     const float* __restrict__ dt_bias,
                                                     unsigned short* __restrict__ betab,
                                                     float* __restrict__ g) {
  int i = blockIdx.x * 256 + threadIdx.x;
  int row = i >> 5, hv = i & 31;
  float rb = bf2f(ba[(size_t)row * 128 + hv]);
  float ra = bf2f(ba[(size_t)row * 128 + 32 + hv]);
  betab[i] = f2bf(1.f / (1.f + expf(-rb)));
  float xg = ra + dt_bias[hv];
  float sp = (xg > 20.f) ? xg : log1pf(expf(xg));
  g[i] = -expf(A_log[hv]) * sp;
}

// ------- conv4 + SiLU + q/k l2norm -------
__global__ __launch_bounds__(256) void conv_kernel(const unsigned short* __restrict__ qkv,
                                                   const float* __restrict__ conv_w,
                                                   unsigned short* __restrict__ out) {
  const int seg = blockIdx.x, tt = blockIdx.y, b = blockIdx.z;
  const int tid = threadIdx.x;
  const int c0 = seg * 128;
  const bool isq = seg < 16;
  int scb;
  if (isq) scb = seg * 512;
  else if (seg < 32) scb = (seg - 16) * 512 + 128;
  else scb = ((seg - 32) >> 1) * 512 + 256 + ((seg - 32) & 1) * 128;

  __shared__ unsigned short raw[35][136];
  __shared__ float cw[4][132];

  for (int i = tid; i < 512; i += 256) {
    int cl = i >> 2, tap = i & 3;
    cw[tap][cl] = conv_w[(size_t)(c0 + cl) * 4 + tap];
  }
  const int t0 = tt * 32;
  for (int i = tid; i < 560; i += 256) {
    int row = i >> 4, col = (i & 15) * 8;
    int gt = t0 - 3 + row;
    uint4 v = make_uint4(0u, 0u, 0u, 0u);
    if (gt >= 0) v = *(const uint4*)(qkv + (size_t)(b * T_LEN + gt) * 8192 + scb + col);
    *(uint4*)(&raw[row][col]) = v;
  }
  __syncthreads();
  const int s = tid >> 3, dg = tid & 7;
  union RawU { uint4 v[2]; unsigned short h[16]; };
  RawU u[4];
  #pragma unroll
  for (int i = 0; i < 4; i++) {
    const uint4* p = (const uint4*)&raw[s + i][dg * 16];
    u[i].v[0] = p[0]; u[i].v[1] = p[1];
  }
  float vals[16]; float ss = 0.f;
  #pragma unroll
  for (int j = 0; j < 16; j++) {
    float a = 0.f;
    #pragma unroll
    for (int i = 0; i < 4; i++) a = fmaf(cw[i][dg * 16 + j], bf2f(u[i].h[j]), a);
    a = a / (1.f + expf(-a));
    vals[j] = a; ss += a * a;
  }
  if (seg < 32) {
    ss += __shfl_xor(ss, 1); ss += __shfl_xor(ss, 2); ss += __shfl_xor(ss, 4);
    float sc = rsqrtf(ss + 1e-6f);
    if (isq) sc *= 0.08838834764831845f;
    #pragma unroll
    for (int j = 0; j < 16; j++) vals[j] *= sc;
  }
  union { uint4 v[2]; unsigned short h[16]; } ov;
  #pragma unroll
  for (int j = 0; j < 16; j++) ov.h[j] = f2bf(vals[j]);
  unsigned short* op = out + (size_t)(b * T_LEN + t0 + s) * 8192 + c0 + dg * 16;
  *(uint4*)(op) = ov.v[0];
  *(uint4*)(op + 8) = ov.v[1];
}

// ---------------- prep: per chunk-head precompute M1, M2, vecs ----------------
__global__ __launch_bounds__(256) void prep_kernel(const unsigned short* __restrict__ conv,
                                                   const float* __restrict__ g,
                                                   const unsigned short* __restrict__ betab,
                                                   unsigned short* __restrict__ M1g,
                                                   unsigned short* __restrict__ M2g,
                                                   unsigned char* __restrict__ vecs) {
  const int c = blockIdx.x, bh = blockIdx.y;
  const int b = bh >> 5, hv = bh & 31, hk = hv >> 1;
  const int bhc = bh * 32 + c;
  const int tid = threadIdx.x, lane = tid & 63, wv = tid >> 6;
  const int r0 = b * T_LEN + c * 64;
  const int l15 = lane & 15, l4 = lane >> 4;

  __shared__ unsigned short Kb[128 * 72];
  __shared__ unsigned short QbX[64 * 136];
  __shared__ unsigned short Lbf[64 * 72];
  __shared__ unsigned short Pb[64 * 72];
  __shared__ unsigned short WT[3 * 16 * 40];
  __shared__ float Gs[64], SCs[64], BLs[64];

  unsigned short* Qb = QbX;
  unsigned short* XTb = QbX;
  unsigned short* Xdrow = QbX + 4608;

  if (wv == 0) {
    float gt = g[(size_t)(r0 + lane) * 32 + hv];
    #pragma unroll
    for (int d = 1; d < 64; d <<= 1) {
      float o = __shfl_up(gt, (unsigned)d, 64);
      if (lane >= d) gt += o;
    }
    float GC = __shfl(gt, 63, 64);
    float lam = expf(gt);
    float beta = bf2f(betab[(size_t)(r0 + lane) * 32 + hv]);
    Gs[lane] = gt;
    SCs[lane] = expf(GC - gt);
    BLs[lane] = beta;
    unsigned short* vb16 = (unsigned short*)(vecs + (size_t)bhc * 272);
    vb16[lane] = f2bf(beta * lam);
    vb16[64 + lane] = f2bf(lam);
    if (lane == 0) *(float*)(vecs + (size_t)bhc * 272 + 256) = expf(GC);
  }
  const unsigned short* Kg = conv + (size_t)r0 * 8192 + 2048 + hk * 128;
  const unsigned short* Qg = conv + (size_t)r0 * 8192 + hk * 128;
  for (int u = tid; u < 1024; u += 256) {
    int row = u >> 4, col = (u & 15) * 8;
    *(uint4*)(&Kb[row * 136 + col]) = *(const uint4*)(Kg + (size_t)row * 8192 + col);
    *(uint4*)(&Qb[row * 136 + col]) = *(const uint4*)(Qg + (size_t)row * 8192 + col);
  }
  __syncthreads();

  {
    f32x4 akk[4], aqk[4];
    #pragma unroll
    for (int st = 0; st < 4; st++) { akk[st] = f32x4{0,0,0,0}; aqk[st] = f32x4{0,0,0,0}; }
    int trow = wv * 16 + l15;
    int klo = l4 * 8;
    #pragma unroll
    for (int ks = 0; ks < 4; ks++) {
      int ko = ks * 32 + klo;
      bf16x8 ak = *(const bf16x8*)(&Kb[trow * 136 + ko]);
      bf16x8 aq = *(const bf16x8*)(&Qb[trow * 136 + ko]);
      #pragma unroll
      for (int st = 0; st < 4; st++) {
        bf16x8 bk = *(const bf16x8*)(&Kb[(st * 16 + l15) * 136 + ko]);
        akk[st] = MFMA(ak, bk, akk[st]);
        aqk[st] = MFMA(aq, bk, aqk[st]);
      }
    }
    int orow = wv * 16 + l4 * 4;
    int oc = l15;
    #pragma unroll
    for (int st = 0; st < 4; st++)
      #pragma unroll
      for (int r = 0; r < 4; r++) {
        int t = orow + r, ssv = st * 16 + oc;
        float e = expf(fminf(Gs[t] - Gs[ssv], 0.f));
        Lbf[t * 72 + ssv] = f2bf((ssv < t) ? BLs[t] * e * akk[st][r] : 0.f);
        Pb[t * 72 + ssv] = f2bf((ssv <= t) ? e * aqk[st][r] : 0.f);
      }
  }
  __syncthreads();

  unsigned short ktv[32];
  {
    int dk = tid >> 1, tb = (tid & 1) * 32;
    #pragma unroll
    for (int i = 0; i < 32; i++)
      ktv[i] = f2bf(bf2f(Kb[(tb + i) * 136 + dk]) * SCs[tb + i]);
    for (int u = tid; u < 896; u += 256) {
      *(uint4*)(&QbX[u * 8]) = make_uint4(0u, 0u, 0u, 0u);
    }
    for (int u = tid; u < 240; u += 256) {
      *(uint4*)(&WT[u * 8]) = make_uint4(0u, 0u, 0u, 0u);
    }
  }
  __syncthreads();

  {
    int dk = tid >> 1, tb = (tid & 1) * 32;
    #pragma unroll
    for (int i = 0; i < 32; i++) Kb[dk * 72 + tb + i] = ktv[i];
  }
  {
    const int w16 = wv * 16;
    const int cc = l15;
    float xr[16];
    #pragma unroll
    for (int t = 0; t < 16; t++) {
      float acc = (cc == t) ? 1.f : 0.f;
      union { uint4 v[2]; unsigned short h[16]; } rw;
      const uint4* p = (const uint4*)(&Lbf[(w16 + t) * 72 + w16]);
      rw.v[0] = p[0]; rw.v[1] = p[1];
      #pragma unroll
      for (int s = 0; s < 16; s++) {
        if (s < t) acc = fmaf(-bf2f(rw.h[s]), xr[s], acc);
      }
      xr[t] = acc;
    }
    if (lane < 16) {
      #pragma unroll
      for (int t = 0; t < 16; t++) {
        unsigned short v = f2bf(xr[t]);
        XTb[(w16 + cc) * 72 + w16 + t] = v;
        Xdrow[wv * 640 + t * 40 + cc] = v;
      }
    }
  }
  __syncthreads();

  if (wv < 3) {
    const int j = wv;
    for (int i = j + 1; i < 4; i++) {
      f32x4 w_ = f32x4{0.f, 0.f, 0.f, 0.f};
      #pragma unroll
      for (int ks = 0; ks < 2; ks++) {
        int so = ks * 32 + l4 * 8;
        bf16x8 af = *(const bf16x8*)(&Lbf[(i * 16 + l15) * 72 + so]);
        bf16x8 bfv = *(const bf16x8*)(&XTb[(j * 16 + l15) * 72 + so]);
        w_ = MFMA(af, bfv, w_);
      }
      #pragma unroll
      for (int r = 0; r < 4; r++)
        WT[j * 640 + l15 * 40 + l4 * 4 + r] = f2bf(-w_[r]);
      f32x4 xij = f32x4{0.f, 0.f, 0.f, 0.f};
      {
        bf16x8 af = *(const bf16x8*)(&Xdrow[i * 640 + l15 * 40 + l4 * 8]);
        bf16x8 bfv = *(const bf16x8*)(&WT[j * 640 + l15 * 40 + l4 * 8]);
        xij = MFMA(af, bfv, xij);
      }
      #pragma unroll
      for (int r = 0; r < 4; r++)
        XTb[(j * 16 + l15) * 72 + i * 16 + l4 * 4 + r] = f2bf(xij[r]);
    }
  }
  __syncthreads();

  for (int tt = wv * 12; tt < wv * 12 + 12; tt++) {
    f32x4 acc = f32x4{0, 0, 0, 0};
    const unsigned short* Abase;
    int mrow, jc;
    if (tt < 16) { mrow = (tt >> 2) * 16; jc = (tt & 3) * 16; Abase = Pb + mrow * 72; }
    else { int i2 = tt - 16; mrow = (i2 >> 2) * 16; jc = (i2 & 3) * 16; Abase = Kb + mrow * 72; }
    #pragma unroll
    for (int ks = 0; ks < 2; ks++) {
      int so = ks * 32 + l4 * 8;
      bf16x8 af = *(const bf16x8*)(Abase + l15 * 72 + so);
      bf16x8 bfv = *(const bf16x8*)(&XTb[(jc + l15) * 72 + so]);
      acc = MFMA(af, bfv, acc);
    }
    int ro = mrow + l4 * 4, co = jc + l15;
    if (tt < 16) {
      #pragma unroll
      for (int r = 0; r < 4; r++)
        M1g[(size_t)bhc * 4096 + (ro + r) * 64 + co] = f2bf(acc[r]);
    } else {
      #pragma unroll
      for (int r = 0; r < 4; r++)
        M2g[(size_t)bhc * 8192 + (ro + r) * 64 + co] = f2bf(acc[r]);
    }
  }
}

// ---------------- sequential chunk recurrence ----------------
__global__ __launch_bounds__(512) void seq_kernel(unsigned short* __restrict__ conv,
                                                  const unsigned short* __restrict__ M1g,
                                                  const unsigned short* __restrict__ M2g,
                                                  const unsigned char* __restrict__ vecs,
                                                  const unsigned short* __restrict__ betab) {
  const int dvs = blockIdx.x, bh = blockIdx.y;
  const int b = bh >> 5, hv = bh & 31, hk = hv >> 1;
  const int dv0 = dvs * 32;
  const int tid = threadIdx.x, lane = tid & 63, wv = tid >> 6;

  __shared__ unsigned short Kb[64 * 136], Qb[64 * 136];
  __shared__ float Sf[128 * 36];
  __shared__ unsigned short S0T[32 * 136];
  __shared__ unsigned short rhsT[32 * 72];

  for (int i = tid; i < 128 * 36; i += 512) Sf[i] = 0.f;
  for (int i = tid; i < 32 * 136; i += 512) S0T[i] = 0;
  __syncthreads();

  const int l15 = lane & 15, l4 = lane >> 4;
  const int trt = (wv >> 1) * 16;
  const int tct = (wv & 1) * 16;

  for (int c = 0; c < 32; c++) {
    const int r0 = b * T_LEN + c * 64;
    const int bhc = bh * 32 + c;
    const unsigned char* vb = vecs + (size_t)bhc * 272;
    const unsigned short* vb16 = (const unsigned short*)vb;
    #pragma unroll
    for (int j = 0; j < 2; j++) {
      int u = tid * 2 + j;
      int row = u >> 4, col = (u & 15) * 8;
      uint4 kv = *(const uint4*)(conv + (size_t)(r0 + row) * 8192 + 2048 + hk * 128 + col);
      uint4 qv = *(const uint4*)(conv + (size_t)(r0 + row) * 8192 + hk * 128 + col);
      *(uint4*)(&Kb[row * 136 + col]) = kv;
      float lam = bf2f(vb16[64 + row]);
      union { uint4 u4; unsigned short h[8]; } qq; qq.u4 = qv;
      #pragma unroll
      for (int e = 0; e < 8; e++) qq.h[e] = f2bf(bf2f(qq.h[e]) * lam);
      *(uint4*)(&Qb[row * 136 + col]) = qq.u4;
    }
    __syncthreads();
    {
      f32x4 acc = f32x4{0, 0, 0, 0};
      #pragma unroll
      for (int ks = 0; ks < 4; ks++) {
        int ko = ks * 32 + l4 * 8;
        bf16x8 af = *(const bf16x8*)(&Kb[(trt + l15) * 136 + ko]);
        bf16x8 bfv = *(const bf16x8*)(&S0T[(tct + l15) * 136 + ko]);
        acc = MFMA(af, bfv, acc);
      }
      #pragma unroll
      for (int r = 0; r < 4; r++) {
        int tl = trt + l4 * 4 + r;
        int t = r0 + tl;
        float beta = bf2f(betab[(size_t)t * 32 + hv]);
        float bl = bf2f(vb16[tl]);
        float vv = bf2f(conv[(size_t)t * 8192 + 4096 + hv * 128 + dv0 + tct + l15]);
        rhsT[(tct + l15) * 72 + tl] = f2bf(beta * vv - bl * acc[r]);
      }
    }
    __syncthreads();
    {
      f32x4 acc = f32x4{0, 0, 0, 0};
      const unsigned short* m1b = M1g + (size_t)bhc * 4096;
      #pragma unroll
      for (int ks = 0; ks < 2; ks++) {
        int so = ks * 32 + l4 * 8;
        union { uint4 u4; bf16x8 h; } af;
        af.u4 = *(const uint4*)(m1b + (trt + l15) * 64 + so);
        bf16x8 bfv = *(const bf16x8*)(&rhsT[(tct + l15) * 72 + so]);
        acc = MFMA(af.h, bfv, acc);
      }
      #pragma unroll
      for (int ks = 0; ks < 4; ks++) {
        int ko = ks * 32 + l4 * 8;
        bf16x8 af = *(const bf16x8*)(&Qb[(trt + l15) * 136 + ko]);
        bf16x8 bfv = *(const bf16x8*)(&S0T[(tct + l15) * 136 + ko]);
        acc = MFMA(af, bfv, acc);
      }
      #pragma unroll
      for (int r = 0; r < 4; r++) {
        int t = r0 + trt + l4 * 4 + r;
        conv[(size_t)t * 8192 + 4096 + hv * 128 + dv0 + tct + l15] = f2bf(acc[r]);
      }
    }
    {
      float lamC = *(const float*)(vb + 256);
      f32x4 sacc[2];
      const unsigned short* m2b = M2g + (size_t)bhc * 8192;
      const int dkb = wv * 16;
      #pragma unroll
      for (int dt = 0; dt < 2; dt++) {
        int dvb = dt * 16;
        f32x4 a;
        #pragma unroll
        for (int r = 0; r < 4; r++) a[r] = lamC * Sf[(dkb + l4 * 4 + r) * 36 + dvb + l15];
        #pragma unroll
        for (int ks = 0; ks < 2; ks++) {
          int so = ks * 32 + l4 * 8;
          union { uint4 u4; bf16x8 h; } af;
          af.u4 = *(const uint4*)(m2b + (dkb + l15) * 64 + so);
          bf16x8 bfv = *(const bf16x8*)(&rhsT[(dvb + l15) * 72 + so]);
          a = MFMA(af.h, bfv, a);
        }
        sacc[dt] = a;
      }
      __syncthreads();
      #pragma unroll
      for (int dt = 0; dt < 2; dt++) {
        int dvb = dt * 16;
        #pragma unroll
        for (int r = 0; r < 4; r++) {
          int dk = dkb + l4 * 4 + r, dvl = dvb + l15;
          Sf[dk * 36 + dvl] = sacc[dt][r];
          S0T[dvl * 136 + dk] = f2bf(sacc[dt][r]);
        }
      }
    }
    __syncthreads();
  }
}

// ---------------- gated RMSNorm in-place on o ----------------
__global__ __launch_bounds__(256) void rmsgate_kernel(unsigned short* __restrict__ conv,
                                                      const unsigned short* __restrict__ zg,
                                                      const float* __restrict__ nw) {
  int wid = blockIdx.x * 4 + (threadIdx.x >> 6);
  int lane = threadIdx.x & 63;
  int row = wid >> 5, hv = wid & 31;
  unsigned short* op = conv + (size_t)row * 8192 + 4096 + hv * 128;
  float o0 = bf2f(op[lane]), o1 = bf2f(op[64 + lane]);
  float ss = o0 * o0 + o1 * o1;
  #pragma unroll
  for (int m = 1; m < 64; m <<= 1) ss += __shfl_xor(ss, m);
  float r = rsqrtf(ss * (1.f / 128.f) + 1e-6f);
  const unsigned short* zp = zg + (size_t)row * 4096 + hv * 128;
  float g0 = bf2f(zp[lane]), g1 = bf2f(zp[64 + lane]);
  g0 = g0 / (1.f + expf(-g0));
  g1 = g1 / (1.f + expf(-g1));
  op[lane] = f2bf(o0 * r * g0 * nw[lane]);
  op[64 + lane] = f2bf(o1 * r * g1 * nw[64 + lane]);
}

extern "C" void kernel_launch(void* const* d_in, const int* in_sizes, int n_in,
                              void* d_out, int out_size, void* d_ws, size_t ws_size,
                              hipStream_t stream) {
  (void)in_sizes; (void)n_in; (void)out_size;
  const float* x       = (const float*)d_in[0];
  const float* W_qkv   = (const float*)d_in[1];
  const float* W_z     = (const float*)d_in[2];
  const float* W_b     = (const float*)d_in[3];
  const float* W_a     = (const float*)d_in[4];
  const float* conv_w  = (const float*)d_in[5];
  const float* dt_bias = (const float*)d_in[6];
  const float* A_log   = (const float*)d_in[7];
  const float* nw      = (const float*)d_in[8];
  const float* W_out   = (const float*)d_in[9];
  float* out = (float*)d_out;

  const size_t NEED = 169115648ULL;
  if (ws_size < NEED) return;

  char* ws = (char*)d_ws;
  unsigned short* qkv_bf = (unsigned short*)(ws + 0);
  unsigned short* M1g    = (unsigned short*)(ws + 0);
  unsigned short* M2g    = (unsigned short*)(ws + 16777216);
  unsigned short* WoutT  = (unsigned short*)(ws + 0);
  unsigned short* zg     = (unsigned short*)(ws + 67108864);
  unsigned short* WzT    = (unsigned short*)(ws + 100663296);
  unsigned short* x_bf   = (unsigned short*)(ws + 100663296 + 16777216);
  unsigned short* WqkvT  = (unsigned short*)(ws + 100663296 + 33554432);
  unsigned short* WbaT   = (unsigned short*)(ws + 100663296 + 33554432);
  unsigned short* ba     = (unsigned short*)(ws + 100663296 + 34078720);
  unsigned short* convb  = (unsigned short*)(ws + 100663296);
  unsigned short* betab  = (unsigned short*)(ws + 167772160);
  float* gbuf            = (float*)(ws + 168034304);
  unsigned char* vecs    = (unsigned char*)(ws + 168558592);

  const int M = MROWS;

  f32_to_bf16_vec<<<(M * 2048 / 4) / 256, 256, 0, stream>>>(x, x_bf, M * 2048 / 4);
  transpose_f2b<<<dim3(8192 / 32, 2048 / 32), 256, 0, stream>>>(W_qkv, WqkvT, 2048, 8192);
  transpose_f2b<<<dim3(4096 / 32, 2048 / 32), 256, 0, stream>>>(W_z, WzT, 2048, 4096);

  // GEMM1: 512x256 tiles, 8x32 = 256 WGs
  gemm512<1><<<256, 1024, 0, stream>>>(x_bf, 2048, WqkvT, 2048, qkv_bf, 8192, M, 8192, 2048);

  transpose_f2b<<<dim3(1, 64), 256, 0, stream>>>(W_b, WbaT, 2048, 32);
  transpose_f2b<<<dim3(1, 64), 256, 0, stream>>>(W_a, WbaT + (size_t)32 * 2048, 2048, 32);

  gemm256<1, 256><<<256, 512, 0, stream>>>(x_bf, 2048, WzT, 2048, zg, 4096, M, 4096, 2048);
  gemm_bf16<1><<<dim3(1, M / 128), 256, 0, stream>>>(x_bf, 2048, WbaT, 2048, ba, 128, M, 128, 2048);

  beta_g_kernel<<<(M * 32) / 256, 256, 0, stream>>>(ba, A_log, dt_bias, betab, gbuf);

  conv_kernel<<<dim3(64, 64, 2), 256, 0, stream>>>(qkv_bf, conv_w, convb);

  prep_kernel<<<dim3(32, 64), 256, 0, stream>>>(convb, gbuf, betab, M1g, M2g, vecs);

  seq_kernel<<<dim3(4, 64), 512, 0, stream>>>(convb, M1g, M2g, vecs, betab);

  rmsgate_kernel<<<32768, 256, 0, stream>>>(convb, zg, nw);

  transpose_f2b<<<dim3(2048 / 32, 4096 / 32), 256, 0, stream>>>(W_out, WoutT, 4096, 2048);
  gemm256<0, 128><<<256, 512, 0, stream>>>(convb + 4096, 8192, WoutT, 4096, out, 2048, M, 2048, 4096);
}

// Round 8
// 626.987 us; speedup vs baseline: 1.7959x; 1.7959x over previous
//
#include <hip/hip_runtime.h>

// Qwen3.5 GatedDeltaNet fwd on gfx950 — chunked delta-rule + 256^2 counted-vmcnt GEMM.
// B=2 T=2048 HID=2048 HK=16 HV=32 DK=DV=128 KW=4, chunk C=64 (32 chunks).
// R7: revert gemm512 (VGPR spill disaster); seq_kernel -> 8 dv-slices x 256thr (2 chains/CU).

#define T_LEN 2048
#define MROWS 4096

typedef __bf16 bf16x8 __attribute__((ext_vector_type(8)));
typedef float f32x4 __attribute__((ext_vector_type(4)));

#define MFMA(a, b, c) __builtin_amdgcn_mfma_f32_16x16x32_bf16((a), (b), (c), 0, 0, 0)

__device__ __forceinline__ unsigned short f2bf(float f) {
  unsigned int u = __float_as_uint(f);
  unsigned int r = (u + 0x7fffu + ((u >> 16) & 1u)) >> 16;
  return (unsigned short)r;
}
__device__ __forceinline__ float bf2f(unsigned short u) {
  return __uint_as_float(((unsigned int)u) << 16);
}
__device__ __forceinline__ void gload_lds16(const void* g, void* l) {
  __builtin_amdgcn_global_load_lds(
      (const __attribute__((address_space(1))) unsigned int*)g,
      (__attribute__((address_space(3))) unsigned int*)l, 16, 0, 0);
}

// ---------------- elementwise f32 -> bf16 ----------------
__global__ __launch_bounds__(256) void f32_to_bf16_vec(const float* __restrict__ src,
                                                       unsigned short* __restrict__ dst,
                                                       int n4) {
  int i = blockIdx.x * 256 + threadIdx.x;
  if (i >= n4) return;
  float4 v = ((const float4*)src)[i];
  ushort4 o;
  o.x = f2bf(v.x); o.y = f2bf(v.y); o.z = f2bf(v.z); o.w = f2bf(v.w);
  ((ushort4*)dst)[i] = o;
}

// ---------------- transpose f32 [R,C] -> bf16 [C,R] ----------------
__global__ __launch_bounds__(256) void transpose_f2b(const float* __restrict__ src,
                                                     unsigned short* __restrict__ dst,
                                                     int R, int C) {
  __shared__ float tile[32][33];
  int tx = threadIdx.x & 31, ty = threadIdx.x >> 5;
  int c0 = blockIdx.x * 32, r0 = blockIdx.y * 32;
  #pragma unroll
  for (int i = ty; i < 32; i += 8)
    tile[i][tx] = src[(size_t)(r0 + i) * C + c0 + tx];
  __syncthreads();
  #pragma unroll
  for (int i = ty; i < 32; i += 8)
    dst[(size_t)(c0 + i) * R + r0 + tx] = f2bf(tile[tx][i]);
}

// ===================== 256-wide-tile GEMM, counted-vmcnt pipeline =====================
template <int OUTBF, int BN>
__global__ __launch_bounds__(512, 2) void gemm256(const unsigned short* __restrict__ A, int lda,
                                                  const unsigned short* __restrict__ Bt, int ldb,
                                                  void* __restrict__ Cv, int ldc,
                                                  int M, int N, int K) {
  constexpr int BUFSZ = 16384 + BN * 64;
  constexpr int BISS = BN / 64;
  constexpr int IS = 4 + BISS;
  constexpr int WMv = (BN == 256) ? 2 : 4;
  constexpr int MSUB = 256 / (WMv * 16);
  constexpr int MSPAN = 256 / WMv;

  __shared__ unsigned short lds[2 * BUFSZ];

  const int mtiles = M >> 8;
  const int nwg = gridDim.x;
  const int orig = blockIdx.x;
  const int q = nwg >> 3, r = nwg & 7;
  const int xcd = orig & 7, idx = orig >> 3;
  const int swz = (xcd < r ? xcd * (q + 1) : r * (q + 1) + (xcd - r) * q) + idx;
  const int m0 = (swz % mtiles) * 256;
  const int n0 = (swz / mtiles) * BN;

  const int tid = threadIdx.x, lane = tid & 63, wv = tid >> 6;
  const int wm = (BN == 256) ? (wv >> 2) : (wv >> 1);
  const int wn = (BN == 256) ? (wv & 3) : (wv & 1);
  const int l15 = lane & 15, l4 = lane >> 4;

  f32x4 acc[MSUB][4];
  #pragma unroll
  for (int i = 0; i < MSUB; i++)
    #pragma unroll
    for (int j = 0; j < 4; j++) acc[i][j] = f32x4{0.f, 0.f, 0.f, 0.f};

  const int NT = K >> 6;

  auto STAGE = [&](int kt) {
    unsigned short* base = lds + (kt & 1) * BUFSZ;
    const int k0 = kt << 6;
    #pragma unroll
    for (int is = 0; is < 4; is++) {
      int ow = is * 8192 + wv * 1024;
      int o = ow + lane * 16;
      int row = o >> 7, colB = o & 127;
      int scol = colB ^ ((row & 7) << 4);
      gload_lds16(A + (size_t)(m0 + row) * lda + k0 + (scol >> 1), base + (ow >> 1));
    }
    #pragma unroll
    for (int is = 0; is < BISS; is++) {
      int ow = is * 8192 + wv * 1024;
      int o = ow + lane * 16;
      int row = o >> 7, colB = o & 127;
      int scol = colB ^ ((row & 7) << 4);
      gload_lds16(Bt + (size_t)(n0 + row) * ldb + k0 + (scol >> 1), base + 16384 + (ow >> 1));
    }
  };

  STAGE(0);
  if (NT > 1) STAGE(1);
  if constexpr (IS == 8) asm volatile("s_waitcnt vmcnt(8)" ::: "memory");
  else                   asm volatile("s_waitcnt vmcnt(6)" ::: "memory");
  __builtin_amdgcn_sched_barrier(0);
  __builtin_amdgcn_s_barrier();
  __builtin_amdgcn_sched_barrier(0);

  for (int t = 0; t < NT; t++) {
    const unsigned short* Abuf = lds + (t & 1) * BUFSZ;
    const unsigned short* Bbuf = Abuf + 16384;
    bf16x8 bF[4][2];
    #pragma unroll
    for (int n = 0; n < 4; n++) {
      int rb = wn * 64 + n * 16 + l15;
      int sw = (rb & 7) << 4;
      #pragma unroll
      for (int ks = 0; ks < 2; ks++) {
        int colB = (ks * 32 + l4 * 8) * 2;
        bF[n][ks] = *(const bf16x8*)(Bbuf + rb * 64 + ((colB ^ sw) >> 1));
      }
    }
    __builtin_amdgcn_s_setprio(1);
    #pragma unroll
    for (int m = 0; m < MSUB; m++) {
      int ra = wm * MSPAN + m * 16 + l15;
      int sw = (ra & 7) << 4;
      int c0b = l4 * 16;
      bf16x8 a0 = *(const bf16x8*)(Abuf + ra * 64 + ((c0b ^ sw) >> 1));
      bf16x8 a1 = *(const bf16x8*)(Abuf + ra * 64 + (((64 + c0b) ^ sw) >> 1));
      #pragma unroll
      for (int n = 0; n < 4; n++) {
        acc[m][n] = MFMA(a0, bF[n][0], acc[m][n]);
        acc[m][n] = MFMA(a1, bF[n][1], acc[m][n]);
      }
    }
    __builtin_amdgcn_s_setprio(0);
    __builtin_amdgcn_sched_barrier(0);
    __builtin_amdgcn_s_barrier();
    __builtin_amdgcn_sched_barrier(0);
    if (t + 2 < NT) STAGE(t + 2);
    if (t + 1 < NT) {
      if (t + 2 < NT) {
        if constexpr (IS == 8) asm volatile("s_waitcnt vmcnt(8)" ::: "memory");
        else                   asm volatile("s_waitcnt vmcnt(6)" ::: "memory");
      } else {
        asm volatile("s_waitcnt vmcnt(0)" ::: "memory");
      }
      __builtin_amdgcn_sched_barrier(0);
      __builtin_amdgcn_s_barrier();
      __builtin_amdgcn_sched_barrier(0);
    }
  }

  #pragma unroll
  for (int m = 0; m < MSUB; m++) {
    int grow = m0 + wm * MSPAN + m * 16 + l4 * 4;
    #pragma unroll
    for (int n = 0; n < 4; n++) {
      int gcol = n0 + wn * 64 + n * 16 + l15;
      if (OUTBF) {
        unsigned short* cp = (unsigned short*)Cv + (size_t)grow * ldc + gcol;
        #pragma unroll
        for (int rr = 0; rr < 4; rr++) cp[(size_t)rr * ldc] = f2bf(acc[m][n][rr]);
      } else {
        float* cp = (float*)Cv + (size_t)grow * ldc + gcol;
        #pragma unroll
        for (int rr = 0; rr < 4; rr++) cp[(size_t)rr * ldc] = acc[m][n][rr];
      }
    }
  }
}

// ------- bf16 MFMA GEMM (128^2, small-N fallback) -------
template <int OUTBF>
__global__ __launch_bounds__(256) void gemm_bf16(const unsigned short* __restrict__ A, int lda,
                                                 const unsigned short* __restrict__ Bt, int ldb,
                                                 void* __restrict__ Cv, int ldc,
                                                 int M, int N, int K) {
  __shared__ unsigned short As[128 * 64];
  __shared__ unsigned short Bs[128 * 64];
  const int tid = threadIdx.x, lane = tid & 63, wv = tid >> 6;
  const int wr = wv >> 1, wc = wv & 1;
  const int m0 = blockIdx.y * 128, n0 = blockIdx.x * 128;
  const int lrow8 = lane >> 3;
  const int lk8 = (lane & 7) * 8;

  f32x4 acc[4][4];
  #pragma unroll
  for (int i = 0; i < 4; i++)
    #pragma unroll
    for (int j = 0; j < 4; j++) acc[i][j] = f32x4{0.f, 0.f, 0.f, 0.f};

  for (int k0 = 0; k0 < K; k0 += 64) {
    #pragma unroll
    for (int j = 0; j < 4; ++j) {
      int chunk = j * 4 + wv;
      int r = chunk * 8 + lrow8;
      gload_lds16(A + (size_t)(m0 + r) * lda + k0 + lk8, (void*)(As + chunk * 512));
      gload_lds16(Bt + (size_t)(n0 + r) * ldb + k0 + lk8, (void*)(Bs + chunk * 512));
    }
    __syncthreads();
    #pragma unroll
    for (int half = 0; half < 2; ++half) {
      int ko = half * 32 + (lane >> 4) * 8;
      bf16x8 af[4], bfr[4];
      #pragma unroll
      for (int i = 0; i < 4; i++) {
        int ra = wr * 64 + i * 16 + (lane & 15);
        af[i] = *(const bf16x8*)(As + ra * 64 + ko);
        int rb = wc * 64 + i * 16 + (lane & 15);
        bfr[i] = *(const bf16x8*)(Bs + rb * 64 + ko);
      }
      #pragma unroll
      for (int i = 0; i < 4; i++)
        #pragma unroll
        for (int j = 0; j < 4; j++)
          acc[i][j] = MFMA(af[i], bfr[j], acc[i][j]);
    }
    __syncthreads();
  }
  int cr4 = (lane >> 4) * 4;
  int cc = lane & 15;
  #pragma unroll
  for (int i = 0; i < 4; i++) {
    int row = m0 + wr * 64 + i * 16 + cr4;
    #pragma unroll
    for (int j = 0; j < 4; j++) {
      int col = n0 + wc * 64 + j * 16 + cc;
      if (OUTBF) {
        unsigned short* cp = (unsigned short*)Cv + (size_t)row * ldc + col;
        #pragma unroll
        for (int r = 0; r < 4; r++) cp[(size_t)r * ldc] = f2bf(acc[i][j][r]);
      } else {
        float* cp = (float*)Cv + (size_t)row * ldc + col;
        #pragma unroll
        for (int r = 0; r < 4; r++) cp[(size_t)r * ldc] = acc[i][j][r];
      }
    }
  }
}

// ---------------- beta / g from ba ----------------
__global__ __launch_bounds__(256) void beta_g_kernel(const unsigned short* __restrict__ ba,
                                                     const float* __restrict__ A_log,
                                                     const float* __restrict__ dt_bias,
                                                     unsigned short* __restrict__ betab,
                                                     float* __restrict__ g) {
  int i = blockIdx.x * 256 + threadIdx.x;
  int row = i >> 5, hv = i & 31;
  float rb = bf2f(ba[(size_t)row * 128 + hv]);
  float ra = bf2f(ba[(size_t)row * 128 + 32 + hv]);
  betab[i] = f2bf(1.f / (1.f + expf(-rb)));
  float xg = ra + dt_bias[hv];
  float sp = (xg > 20.f) ? xg : log1pf(expf(xg));
  g[i] = -expf(A_log[hv]) * sp;
}

// ------- conv4 + SiLU + q/k l2norm -------
__global__ __launch_bounds__(256) void conv_kernel(const unsigned short* __restrict__ qkv,
                                                   const float* __restrict__ conv_w,
                                                   unsigned short* __restrict__ out) {
  const int seg = blockIdx.x, tt = blockIdx.y, b = blockIdx.z;
  const int tid = threadIdx.x;
  const int c0 = seg * 128;
  const bool isq = seg < 16;
  int scb;
  if (isq) scb = seg * 512;
  else if (seg < 32) scb = (seg - 16) * 512 + 128;
  else scb = ((seg - 32) >> 1) * 512 + 256 + ((seg - 32) & 1) * 128;

  __shared__ unsigned short raw[35][136];
  __shared__ float cw[4][132];

  for (int i = tid; i < 512; i += 256) {
    int cl = i >> 2, tap = i & 3;
    cw[tap][cl] = conv_w[(size_t)(c0 + cl) * 4 + tap];
  }
  const int t0 = tt * 32;
  for (int i = tid; i < 560; i += 256) {
    int row = i >> 4, col = (i & 15) * 8;
    int gt = t0 - 3 + row;
    uint4 v = make_uint4(0u, 0u, 0u, 0u);
    if (gt >= 0) v = *(const uint4*)(qkv + (size_t)(b * T_LEN + gt) * 8192 + scb + col);
    *(uint4*)(&raw[row][col]) = v;
  }
  __syncthreads();
  const int s = tid >> 3, dg = tid & 7;
  union RawU { uint4 v[2]; unsigned short h[16]; };
  RawU u[4];
  #pragma unroll
  for (int i = 0; i < 4; i++) {
    const uint4* p = (const uint4*)&raw[s + i][dg * 16];
    u[i].v[0] = p[0]; u[i].v[1] = p[1];
  }
  float vals[16]; float ss = 0.f;
  #pragma unroll
  for (int j = 0; j < 16; j++) {
    float a = 0.f;
    #pragma unroll
    for (int i = 0; i < 4; i++) a = fmaf(cw[i][dg * 16 + j], bf2f(u[i].h[j]), a);
    a = a / (1.f + expf(-a));
    vals[j] = a; ss += a * a;
  }
  if (seg < 32) {
    ss += __shfl_xor(ss, 1); ss += __shfl_xor(ss, 2); ss += __shfl_xor(ss, 4);
    float sc = rsqrtf(ss + 1e-6f);
    if (isq) sc *= 0.08838834764831845f;
    #pragma unroll
    for (int j = 0; j < 16; j++) vals[j] *= sc;
  }
  union { uint4 v[2]; unsigned short h[16]; } ov;
  #pragma unroll
  for (int j = 0; j < 16; j++) ov.h[j] = f2bf(vals[j]);
  unsigned short* op = out + (size_t)(b * T_LEN + t0 + s) * 8192 + c0 + dg * 16;
  *(uint4*)(op) = ov.v[0];
  *(uint4*)(op + 8) = ov.v[1];
}

// ---------------- prep: per chunk-head precompute M1, M2, vecs ----------------
__global__ __launch_bounds__(256) void prep_kernel(const unsigned short* __restrict__ conv,
                                                   const float* __restrict__ g,
                                                   const unsigned short* __restrict__ betab,
                                                   unsigned short* __restrict__ M1g,
                                                   unsigned short* __restrict__ M2g,
                                                   unsigned char* __restrict__ vecs) {
  const int c = blockIdx.x, bh = blockIdx.y;
  const int b = bh >> 5, hv = bh & 31, hk = hv >> 1;
  const int bhc = bh * 32 + c;
  const int tid = threadIdx.x, lane = tid & 63, wv = tid >> 6;
  const int r0 = b * T_LEN + c * 64;
  const int l15 = lane & 15, l4 = lane >> 4;

  __shared__ unsigned short Kb[128 * 72];
  __shared__ unsigned short QbX[64 * 136];
  __shared__ unsigned short Lbf[64 * 72];
  __shared__ unsigned short Pb[64 * 72];
  __shared__ unsigned short WT[3 * 16 * 40];
  __shared__ float Gs[64], SCs[64], BLs[64];

  unsigned short* Qb = QbX;
  unsigned short* XTb = QbX;
  unsigned short* Xdrow = QbX + 4608;

  if (wv == 0) {
    float gt = g[(size_t)(r0 + lane) * 32 + hv];
    #pragma unroll
    for (int d = 1; d < 64; d <<= 1) {
      float o = __shfl_up(gt, (unsigned)d, 64);
      if (lane >= d) gt += o;
    }
    float GC = __shfl(gt, 63, 64);
    float lam = expf(gt);
    float beta = bf2f(betab[(size_t)(r0 + lane) * 32 + hv]);
    Gs[lane] = gt;
    SCs[lane] = expf(GC - gt);
    BLs[lane] = beta;
    unsigned short* vb16 = (unsigned short*)(vecs + (size_t)bhc * 272);
    vb16[lane] = f2bf(beta * lam);
    vb16[64 + lane] = f2bf(lam);
    if (lane == 0) *(float*)(vecs + (size_t)bhc * 272 + 256) = expf(GC);
  }
  const unsigned short* Kg = conv + (size_t)r0 * 8192 + 2048 + hk * 128;
  const unsigned short* Qg = conv + (size_t)r0 * 8192 + hk * 128;
  for (int u = tid; u < 1024; u += 256) {
    int row = u >> 4, col = (u & 15) * 8;
    *(uint4*)(&Kb[row * 136 + col]) = *(const uint4*)(Kg + (size_t)row * 8192 + col);
    *(uint4*)(&Qb[row * 136 + col]) = *(const uint4*)(Qg + (size_t)row * 8192 + col);
  }
  __syncthreads();

  {
    f32x4 akk[4], aqk[4];
    #pragma unroll
    for (int st = 0; st < 4; st++) { akk[st] = f32x4{0,0,0,0}; aqk[st] = f32x4{0,0,0,0}; }
    int trow = wv * 16 + l15;
    int klo = l4 * 8;
    #pragma unroll
    for (int ks = 0; ks < 4; ks++) {
      int ko = ks * 32 + klo;
      bf16x8 ak = *(const bf16x8*)(&Kb[trow * 136 + ko]);
      bf16x8 aq = *(const bf16x8*)(&Qb[trow * 136 + ko]);
      #pragma unroll
      for (int st = 0; st < 4; st++) {
        bf16x8 bk = *(const bf16x8*)(&Kb[(st * 16 + l15) * 136 + ko]);
        akk[st] = MFMA(ak, bk, akk[st]);
        aqk[st] = MFMA(aq, bk, aqk[st]);
      }
    }
    int orow = wv * 16 + l4 * 4;
    int oc = l15;
    #pragma unroll
    for (int st = 0; st < 4; st++)
      #pragma unroll
      for (int r = 0; r < 4; r++) {
        int t = orow + r, ssv = st * 16 + oc;
        float e = expf(fminf(Gs[t] - Gs[ssv], 0.f));
        Lbf[t * 72 + ssv] = f2bf((ssv < t) ? BLs[t] * e * akk[st][r] : 0.f);
        Pb[t * 72 + ssv] = f2bf((ssv <= t) ? e * aqk[st][r] : 0.f);
      }
  }
  __syncthreads();

  unsigned short ktv[32];
  {
    int dk = tid >> 1, tb = (tid & 1) * 32;
    #pragma unroll
    for (int i = 0; i < 32; i++)
      ktv[i] = f2bf(bf2f(Kb[(tb + i) * 136 + dk]) * SCs[tb + i]);
    for (int u = tid; u < 896; u += 256) {
      *(uint4*)(&QbX[u * 8]) = make_uint4(0u, 0u, 0u, 0u);
    }
    for (int u = tid; u < 240; u += 256) {
      *(uint4*)(&WT[u * 8]) = make_uint4(0u, 0u, 0u, 0u);
    }
  }
  __syncthreads();

  {
    int dk = tid >> 1, tb = (tid & 1) * 32;
    #pragma unroll
    for (int i = 0; i < 32; i++) Kb[dk * 72 + tb + i] = ktv[i];
  }
  {
    const int w16 = wv * 16;
    const int cc = l15;
    float xr[16];
    #pragma unroll
    for (int t = 0; t < 16; t++) {
      float acc = (cc == t) ? 1.f : 0.f;
      union { uint4 v[2]; unsigned short h[16]; } rw;
      const uint4* p = (const uint4*)(&Lbf[(w16 + t) * 72 + w16]);
      rw.v[0] = p[0]; rw.v[1] = p[1];
      #pragma unroll
      for (int s = 0; s < 16; s++) {
        if (s < t) acc = fmaf(-bf2f(rw.h[s]), xr[s], acc);
      }
      xr[t] = acc;
    }
    if (lane < 16) {
      #pragma unroll
      for (int t = 0; t < 16; t++) {
        unsigned short v = f2bf(xr[t]);
        XTb[(w16 + cc) * 72 + w16 + t] = v;
        Xdrow[wv * 640 + t * 40 + cc] = v;
      }
    }
  }
  __syncthreads();

  if (wv < 3) {
    const int j = wv;
    for (int i = j + 1; i < 4; i++) {
      f32x4 w_ = f32x4{0.f, 0.f, 0.f, 0.f};
      #pragma unroll
      for (int ks = 0; ks < 2; ks++) {
        int so = ks * 32 + l4 * 8;
        bf16x8 af = *(const bf16x8*)(&Lbf[(i * 16 + l15) * 72 + so]);
        bf16x8 bfv = *(const bf16x8*)(&XTb[(j * 16 + l15) * 72 + so]);
        w_ = MFMA(af, bfv, w_);
      }
      #pragma unroll
      for (int r = 0; r < 4; r++)
        WT[j * 640 + l15 * 40 + l4 * 4 + r] = f2bf(-w_[r]);
      f32x4 xij = f32x4{0.f, 0.f, 0.f, 0.f};
      {
        bf16x8 af = *(const bf16x8*)(&Xdrow[i * 640 + l15 * 40 + l4 * 8]);
        bf16x8 bfv = *(const bf16x8*)(&WT[j * 640 + l15 * 40 + l4 * 8]);
        xij = MFMA(af, bfv, xij);
      }
      #pragma unroll
      for (int r = 0; r < 4; r++)
        XTb[(j * 16 + l15) * 72 + i * 16 + l4 * 4 + r] = f2bf(xij[r]);
    }
  }
  __syncthreads();

  for (int tt = wv * 12; tt < wv * 12 + 12; tt++) {
    f32x4 acc = f32x4{0, 0, 0, 0};
    const unsigned short* Abase;
    int mrow, jc;
    if (tt < 16) { mrow = (tt >> 2) * 16; jc = (tt & 3) * 16; Abase = Pb + mrow * 72; }
    else { int i2 = tt - 16; mrow = (i2 >> 2) * 16; jc = (i2 & 3) * 16; Abase = Kb + mrow * 72; }
    #pragma unroll
    for (int ks = 0; ks < 2; ks++) {
      int so = ks * 32 + l4 * 8;
      bf16x8 af = *(const bf16x8*)(Abase + l15 * 72 + so);
      bf16x8 bfv = *(const bf16x8*)(&XTb[(jc + l15) * 72 + so]);
      acc = MFMA(af, bfv, acc);
    }
    int ro = mrow + l4 * 4, co = jc + l15;
    if (tt < 16) {
      #pragma unroll
      for (int r = 0; r < 4; r++)
        M1g[(size_t)bhc * 4096 + (ro + r) * 64 + co] = f2bf(acc[r]);
    } else {
      #pragma unroll
      for (int r = 0; r < 4; r++)
        M2g[(size_t)bhc * 8192 + (ro + r) * 64 + co] = f2bf(acc[r]);
    }
  }
}

// ---------------- sequential chunk recurrence ----------------
// grid (8 dv-slices of 16, 64 bh); block 256 (4 waves) -> 2 chains/CU.
__global__ __launch_bounds__(256) void seq_kernel(unsigned short* __restrict__ conv,
                                                  const unsigned short* __restrict__ M1g,
                                                  const unsigned short* __restrict__ M2g,
                                                  const unsigned char* __restrict__ vecs,
                                                  const unsigned short* __restrict__ betab) {
  const int dvs = blockIdx.x, bh = blockIdx.y;
  const int b = bh >> 5, hv = bh & 31, hk = hv >> 1;
  const int dv0 = dvs * 16;
  const int tid = threadIdx.x, lane = tid & 63, wv = tid >> 6;

  __shared__ unsigned short Kb[64 * 136], Qb[64 * 136];
  __shared__ float Sf[128 * 20];
  __shared__ unsigned short S0T[16 * 136];
  __shared__ unsigned short rhsT[16 * 72];

  for (int i = tid; i < 128 * 20; i += 256) Sf[i] = 0.f;
  for (int i = tid; i < 16 * 136; i += 256) S0T[i] = 0;
  __syncthreads();

  const int l15 = lane & 15, l4 = lane >> 4;
  const int trt = wv * 16;   // 4 waves x 16 t-rows

  for (int c = 0; c < 32; c++) {
    const int r0 = b * T_LEN + c * 64;
    const int bhc = bh * 32 + c;
    const unsigned char* vb = vecs + (size_t)bhc * 272;
    const unsigned short* vb16 = (const unsigned short*)vb;
    // stage K, Qhat (= Lambda_t * q_t): 1024 uint4 over 256 threads
    #pragma unroll
    for (int j = 0; j < 4; j++) {
      int u = j * 256 + tid;
      int row = u >> 4, col = (u & 15) * 8;
      uint4 kv = *(const uint4*)(conv + (size_t)(r0 + row) * 8192 + 2048 + hk * 128 + col);
      uint4 qv = *(const uint4*)(conv + (size_t)(r0 + row) * 8192 + hk * 128 + col);
      *(uint4*)(&Kb[row * 136 + col]) = kv;
      float lam = bf2f(vb16[64 + row]);
      union { uint4 u4; unsigned short h[8]; } qq; qq.u4 = qv;
      #pragma unroll
      for (int e = 0; e < 8; e++) qq.h[e] = f2bf(bf2f(qq.h[e]) * lam);
      *(uint4*)(&Qb[row * 136 + col]) = qq.u4;
    }
    __syncthreads();
    // KS0 -> rhsT
    {
      f32x4 acc = f32x4{0, 0, 0, 0};
      #pragma unroll
      for (int ks = 0; ks < 4; ks++) {
        int ko = ks * 32 + l4 * 8;
        bf16x8 af = *(const bf16x8*)(&Kb[(trt + l15) * 136 + ko]);
        bf16x8 bfv = *(const bf16x8*)(&S0T[l15 * 136 + ko]);
        acc = MFMA(af, bfv, acc);
      }
      #pragma unroll
      for (int r = 0; r < 4; r++) {
        int tl = trt + l4 * 4 + r;
        int t = r0 + tl;
        float beta = bf2f(betab[(size_t)t * 32 + hv]);
        float bl = bf2f(vb16[tl]);
        float vv = bf2f(conv[(size_t)t * 8192 + 4096 + hv * 128 + dv0 + l15]);
        rhsT[l15 * 72 + tl] = f2bf(beta * vv - bl * acc[r]);
      }
    }
    __syncthreads();
    // O = M1@rhsT + Qhat@S0T -> write o over v
    {
      f32x4 acc = f32x4{0, 0, 0, 0};
      const unsigned short* m1b = M1g + (size_t)bhc * 4096;
      #pragma unroll
      for (int ks = 0; ks < 2; ks++) {
        int so = ks * 32 + l4 * 8;
        union { uint4 u4; bf16x8 h; } af;
        af.u4 = *(const uint4*)(m1b + (trt + l15) * 64 + so);
        bf16x8 bfv = *(const bf16x8*)(&rhsT[l15 * 72 + so]);
        acc = MFMA(af.h, bfv, acc);
      }
      #pragma unroll
      for (int ks = 0; ks < 4; ks++) {
        int ko = ks * 32 + l4 * 8;
        bf16x8 af = *(const bf16x8*)(&Qb[(trt + l15) * 136 + ko]);
        bf16x8 bfv = *(const bf16x8*)(&S0T[l15 * 136 + ko]);
        acc = MFMA(af, bfv, acc);
      }
      #pragma unroll
      for (int r = 0; r < 4; r++) {
        int t = r0 + trt + l4 * 4 + r;
        conv[(size_t)t * 8192 + 4096 + hv * 128 + dv0 + l15] = f2bf(acc[r]);
      }
    }
    // S = LambdaC*S0 + M2@rhsT  (each wave: 2 dk-tiles of 16)
    {
      float lamC = *(const float*)(vb + 256);
      f32x4 sacc[2];
      const unsigned short* m2b = M2g + (size_t)bhc * 8192;
      #pragma unroll
      for (int dkt = 0; dkt < 2; dkt++) {
        int dkb = (wv * 2 + dkt) * 16;
        f32x4 a;
        #pragma unroll
        for (int r = 0; r < 4; r++) a[r] = lamC * Sf[(dkb + l4 * 4 + r) * 20 + l15];
        #pragma unroll
        for (int ks = 0; ks < 2; ks++) {
          int so = ks * 32 + l4 * 8;
          union { uint4 u4; bf16x8 h; } af;
          af.u4 = *(const uint4*)(m2b + (dkb + l15) * 64 + so);
          bf16x8 bfv = *(const bf16x8*)(&rhsT[l15 * 72 + so]);
          a = MFMA(af.h, bfv, a);
        }
        sacc[dkt] = a;
      }
      __syncthreads();   // all reads of S0T/Sf/rhsT complete
      #pragma unroll
      for (int dkt = 0; dkt < 2; dkt++) {
        int dkb = (wv * 2 + dkt) * 16;
        #pragma unroll
        for (int r = 0; r < 4; r++) {
          int dk = dkb + l4 * 4 + r;
          Sf[dk * 20 + l15] = sacc[dkt][r];
          S0T[l15 * 136 + dk] = f2bf(sacc[dkt][r]);
        }
      }
    }
    __syncthreads();
  }
}

// ---------------- gated RMSNorm in-place on o ----------------
__global__ __launch_bounds__(256) void rmsgate_kernel(unsigned short* __restrict__ conv,
                                                      const unsigned short* __restrict__ zg,
                                                      const float* __restrict__ nw) {
  int wid = blockIdx.x * 4 + (threadIdx.x >> 6);
  int lane = threadIdx.x & 63;
  int row = wid >> 5, hv = wid & 31;
  unsigned short* op = conv + (size_t)row * 8192 + 4096 + hv * 128;
  float o0 = bf2f(op[lane]), o1 = bf2f(op[64 + lane]);
  float ss = o0 * o0 + o1 * o1;
  #pragma unroll
  for (int m = 1; m < 64; m <<= 1) ss += __shfl_xor(ss, m);
  float r = rsqrtf(ss * (1.f / 128.f) + 1e-6f);
  const unsigned short* zp = zg + (size_t)row * 4096 + hv * 128;
  float g0 = bf2f(zp[lane]), g1 = bf2f(zp[64 + lane]);
  g0 = g0 / (1.f + expf(-g0));
  g1 = g1 / (1.f + expf(-g1));
  op[lane] = f2bf(o0 * r * g0 * nw[lane]);
  op[64 + lane] = f2bf(o1 * r * g1 * nw[64 + lane]);
}

extern "C" void kernel_launch(void* const* d_in, const int* in_sizes, int n_in,
                              void* d_out, int out_size, void* d_ws, size_t ws_size,
                              hipStream_t stream) {
  (void)in_sizes; (void)n_in; (void)out_size;
  const float* x       = (const float*)d_in[0];
  const float* W_qkv   = (const float*)d_in[1];
  const float* W_z     = (const float*)d_in[2];
  const float* W_b     = (const float*)d_in[3];
  const float* W_a     = (const float*)d_in[4];
  const float* conv_w  = (const float*)d_in[5];
  const float* dt_bias = (const float*)d_in[6];
  const float* A_log   = (const float*)d_in[7];
  const float* nw      = (const float*)d_in[8];
  const float* W_out   = (const float*)d_in[9];
  float* out = (float*)d_out;

  const size_t NEED = 169115648ULL;
  if (ws_size < NEED) return;

  char* ws = (char*)d_ws;
  unsigned short* qkv_bf = (unsigned short*)(ws + 0);
  unsigned short* M1g    = (unsigned short*)(ws + 0);
  unsigned short* M2g    = (unsigned short*)(ws + 16777216);
  unsigned short* WoutT  = (unsigned short*)(ws + 0);
  unsigned short* zg     = (unsigned short*)(ws + 67108864);
  unsigned short* WzT    = (unsigned short*)(ws + 100663296);
  unsigned short* x_bf   = (unsigned short*)(ws + 100663296 + 16777216);
  unsigned short* WqkvT  = (unsigned short*)(ws + 100663296 + 33554432);
  unsigned short* WbaT   = (unsigned short*)(ws + 100663296 + 33554432);
  unsigned short* ba     = (unsigned short*)(ws + 100663296 + 34078720);
  unsigned short* convb  = (unsigned short*)(ws + 100663296);
  unsigned short* betab  = (unsigned short*)(ws + 167772160);
  float* gbuf            = (float*)(ws + 168034304);
  unsigned char* vecs    = (unsigned char*)(ws + 168558592);

  const int M = MROWS;

  f32_to_bf16_vec<<<(M * 2048 / 4) / 256, 256, 0, stream>>>(x, x_bf, M * 2048 / 4);
  transpose_f2b<<<dim3(8192 / 32, 2048 / 32), 256, 0, stream>>>(W_qkv, WqkvT, 2048, 8192);
  transpose_f2b<<<dim3(4096 / 32, 2048 / 32), 256, 0, stream>>>(W_z, WzT, 2048, 4096);

  gemm256<1, 256><<<512, 512, 0, stream>>>(x_bf, 2048, WqkvT, 2048, qkv_bf, 8192, M, 8192, 2048);

  transpose_f2b<<<dim3(1, 64), 256, 0, stream>>>(W_b, WbaT, 2048, 32);
  transpose_f2b<<<dim3(1, 64), 256, 0, stream>>>(W_a, WbaT + (size_t)32 * 2048, 2048, 32);

  gemm256<1, 256><<<256, 512, 0, stream>>>(x_bf, 2048, WzT, 2048, zg, 4096, M, 4096, 2048);
  gemm_bf16<1><<<dim3(1, M / 128), 256, 0, stream>>>(x_bf, 2048, WbaT, 2048, ba, 128, M, 128, 2048);

  beta_g_kernel<<<(M * 32) / 256, 256, 0, stream>>>(ba, A_log, dt_bias, betab, gbuf);

  conv_kernel<<<dim3(64, 64, 2), 256, 0, stream>>>(qkv_bf, conv_w, convb);

  prep_kernel<<<dim3(32, 64), 256, 0, stream>>>(convb, gbuf, betab, M1g, M2g, vecs);

  seq_kernel<<<dim3(8, 64), 256, 0, stream>>>(convb, M1g, M2g, vecs, betab);

  rmsgate_kernel<<<32768, 256, 0, stream>>>(convb, zg, nw);

  transpose_f2b<<<dim3(2048 / 32, 4096 / 32), 256, 0, stream>>>(W_out, WoutT, 4096, 2048);
  gemm256<0, 128><<<256, 512, 0, stream>>>(convb + 4096, 8192, WoutT, 4096, out, 2048, M, 2048, 4096);
}